// Round 6
// baseline (25.053 us; speedup 1.0000x reference)
//
#include <hip/hip_runtime.h>

namespace {
constexpr int Bn = 64;
constexpr int Ln = 512;
constexpr int Hn = 768;
constexpr int Dn = 16;
constexpr float NEGV = -900000.0f;  // (kept for reference; unused — masked rows never touched)
}

// ---------------------------------------------------------------------------
// Online-softmax fused kernel. blocks [0,Bn): query; [Bn,Bn+Bn*Dn): doc.
// Wave w owns rows {w, w+4, ...}. Per row: load 3 float4 (lane+64j covers all
// 768 cols), score = all-lane shfl_xor reduce of the dot, then flash update:
//   if (p > m) { sc=exp(m-p); acc*=sc; l*=sc; m=p; }   // wave-uniform branch
//   e = exp(p-m); acc += e*row; l += e;
// Row registers die immediately -> VGPR ~half of R5 -> 2x occupancy.
// ONE barrier total: cross-wave flash combine (m_w, l_w, acc_w) through LDS.
// Every hidden_states byte is read exactly once, as dwordx4.
// ---------------------------------------------------------------------------
template<int NIT>
__device__ __forceinline__ void flash_span(
    const float* __restrict__ rowbase,   // &hs[(b*L + first_row) * H]
    const float* __restrict__ W, float bias, int len,
    float4 (*pool4)[192], float* m_sh, float* l_sh,
    int t, int wave, int lane, float4 out4[3])
{
    float4 wv[3];
#pragma unroll
    for (int j = 0; j < 3; ++j)
        wv[j] = *reinterpret_cast<const float4*>(W + (lane + 64 * j) * 4);

    float4 acc[3];
#pragma unroll
    for (int j = 0; j < 3; ++j) acc[j] = make_float4(0.f, 0.f, 0.f, 0.f);
    float m = -INFINITY, l = 0.f;

#pragma unroll
    for (int it = 0; it < NIT; ++it) {
        const int s = wave + 4 * it;                  // wave-uniform predicate
        if (s < len) {
            const float* r = rowbase + s * Hn;
            float4 c0 = *reinterpret_cast<const float4*>(r + lane * 4);
            float4 c1 = *reinterpret_cast<const float4*>(r + (lane + 64) * 4);
            float4 c2 = *reinterpret_cast<const float4*>(r + (lane + 128) * 4);
            float p = c0.x * wv[0].x + c0.y * wv[0].y + c0.z * wv[0].z + c0.w * wv[0].w
                    + c1.x * wv[1].x + c1.y * wv[1].y + c1.z * wv[1].z + c1.w * wv[1].w
                    + c2.x * wv[2].x + c2.y * wv[2].y + c2.z * wv[2].z + c2.w * wv[2].w;
#pragma unroll
            for (int off = 32; off; off >>= 1) p += __shfl_xor(p, off);
            p += bias;
            if (p > m) {                              // wave-uniform (p reduced)
                const float sc = __expf(m - p);       // first iter: exp(-inf)=0
                acc[0].x *= sc; acc[0].y *= sc; acc[0].z *= sc; acc[0].w *= sc;
                acc[1].x *= sc; acc[1].y *= sc; acc[1].z *= sc; acc[1].w *= sc;
                acc[2].x *= sc; acc[2].y *= sc; acc[2].z *= sc; acc[2].w *= sc;
                l *= sc; m = p;
            }
            const float e = __expf(p - m);
            acc[0].x += e * c0.x; acc[0].y += e * c0.y; acc[0].z += e * c0.z; acc[0].w += e * c0.w;
            acc[1].x += e * c1.x; acc[1].y += e * c1.y; acc[1].z += e * c1.z; acc[1].w += e * c1.w;
            acc[2].x += e * c2.x; acc[2].y += e * c2.y; acc[2].z += e * c2.z; acc[2].w += e * c2.w;
            l += e;
        }
    }

    // cross-wave flash combine (single barrier)
#pragma unroll
    for (int j = 0; j < 3; ++j) pool4[wave][lane + 64 * j] = acc[j];
    if (lane == 0) { m_sh[wave] = m; l_sh[wave] = l; }
    __syncthreads();

    const float m0 = m_sh[0], m1 = m_sh[1], m2 = m_sh[2], m3 = m_sh[3];
    const float M = fmaxf(fmaxf(m0, m1), fmaxf(m2, m3));
    const float w0 = __expf(m0 - M), w1 = __expf(m1 - M),
                w2 = __expf(m2 - M), w3 = __expf(m3 - M);
    const float L = l_sh[0] * w0 + l_sh[1] * w1 + l_sh[2] * w2 + l_sh[3] * w3;
    const float inv = 1.f / L;
#pragma unroll
    for (int j = 0; j < 3; ++j) {
        const int col = lane + 64 * j;
        const float4 s0 = pool4[0][col], s1 = pool4[1][col],
                     s2 = pool4[2][col], s3 = pool4[3][col];
        out4[j].x = (s0.x * w0 + s1.x * w1 + s2.x * w2 + s3.x * w3) * inv;
        out4[j].y = (s0.y * w0 + s1.y * w1 + s2.y * w2 + s3.y * w3) * inv;
        out4[j].z = (s0.z * w0 + s1.z * w1 + s2.z * w2 + s3.z * w3) * inv;
        out4[j].w = (s0.w * w0 + s1.w * w1 + s2.w * w2 + s3.w * w3) * inv;
    }
}

__global__ __launch_bounds__(256) void k_fused(
    const float* __restrict__ hs,
    const float* __restrict__ Wd, const float* __restrict__ bd,
    const float* __restrict__ Wq, const float* __restrict__ bq,
    const int* __restrict__ qlen, const int* __restrict__ slens,
    float* __restrict__ out_doc, float* __restrict__ out_q)
{
    __shared__ float4 pool4[4][192];      // 12 KB
    __shared__ float m_sh[4], l_sh[4];

    const int t = threadIdx.x;
    const int wave = t >> 6;
    const int lane = t & 63;
    const int bid = blockIdx.x;

    if (bid < Bn) {
        // ------------------------- query block -------------------------
        const int b = bid;
        const int ql = qlen[b];                            // 8..32
        const float* bp = hs + ((size_t)b * Ln + 1) * Hn;
        float4 o4[3];
        flash_span<8>(bp, Wq, bq[0], ql, pool4, m_sh, l_sh, t, wave, lane, o4);
        for (int dd = 0; dd < Dn; ++dd) {
            float4* o = reinterpret_cast<float4*>(out_q + ((size_t)b * Dn + dd) * Hn);
            o[lane]       = o4[0];
            o[lane + 64]  = o4[1];
            o[lane + 128] = o4[2];
        }
    } else {
        // -------------------------- doc block --------------------------
        const int id = bid - Bn;
        const int b = id >> 4;
        const int d = id & 15;

        const int sv = slens[b * Dn + (lane & 15)];        // parallel prefix
        const int sl = __shfl(sv, d, 64);                  // this doc's len
        float4* o = reinterpret_cast<float4*>(out_doc + ((size_t)b * Dn + d) * Hn);
        if (sl == 0) {                                     // ~36% of doc blocks
            const float4 z = make_float4(0.f, 0.f, 0.f, 0.f);
            o[lane] = z; o[lane + 64] = z; o[lane + 128] = z;
            return;
        }
        int pref = 0;
#pragma unroll
        for (int k = 0; k < Dn; ++k)
            pref += (k < d) ? __shfl(sv, k, 64) : 0;
        const int base = qlen[b] + 2 + pref;               // max valid idx 481 < 512
        const float* bp = hs + ((size_t)b * Ln + base) * Hn;
        float4 o4[3];
        flash_span<7>(bp, Wd, bd[0], sl, pool4, m_sh, l_sh, t, wave, lane, o4);
        o[lane]       = o4[0];
        o[lane + 64]  = o4[1];
        o[lane + 128] = o4[2];
    }
}

extern "C" void kernel_launch(void* const* d_in, const int* in_sizes, int n_in,
                              void* d_out, int out_size, void* d_ws, size_t ws_size,
                              hipStream_t stream)
{
    const float* hs    = (const float*)d_in[0];   // (B,L,H) f32
    const float* Wd    = (const float*)d_in[1];   // (H,1)
    const float* bd    = (const float*)d_in[2];   // (1,)
    const float* Wq    = (const float*)d_in[3];   // (H,1)
    const float* bq    = (const float*)d_in[4];   // (1,)
    const int*   qlen  = (const int*)d_in[5];     // (B,)
    const int*   slens = (const int*)d_in[6];     // (B,D)

    float* out_doc = (float*)d_out;                       // (B,D,H) doc_pooled
    float* out_q   = out_doc + (size_t)Bn * Dn * Hn;      // (B,D,H) q_bcast

    k_fused<<<Bn + Bn * Dn, 256, 0, stream>>>(hs, Wd, bd, Wq, bq,
                                              qlen, slens, out_doc, out_q);
}

// Round 7
// 17.807 us; speedup vs baseline: 1.4069x; 1.4069x over previous
//
#include <hip/hip_runtime.h>

namespace {
constexpr int Bn = 64;
constexpr int Ln = 512;
constexpr int Hn = 768;
constexpr int Dn = 16;
constexpr float NEGV = -900000.0f;
}

// ---------------------------------------------------------------------------
// R5 structure (single-read, register-keep, independent iterations), widened:
//   512 threads = 8 waves per task; wave w owns rows {w, w+8, ...} -> NIT=4.
//   Phase 1: load 3 float4/lane per row (lane+64j covers 768 cols), dot with
//            W, 6-step shfl_xor reduce, lane0 -> score_sh[s]. Rows stay in c[].
//   One barrier.
//   Softmax: computed REDUNDANTLY by every wave (width-32 shfl_xor in both
//            halves) from score_sh -> no second barrier. alpha[s] fetched by
//            in-wave __shfl.
//   Phase 2: pure register FMA; 8 wave partials combine via 24 KB LDS (one
//            barrier), threads 0..191 sum and store float4.
// Every hidden_states byte read exactly once, as dwordx4.
// ---------------------------------------------------------------------------
__global__ __launch_bounds__(512) void k_fused(
    const float* __restrict__ hs,
    const float* __restrict__ Wd, const float* __restrict__ bd,
    const float* __restrict__ Wq, const float* __restrict__ bq,
    const int* __restrict__ qlen, const int* __restrict__ slens,
    float* __restrict__ out_doc, float* __restrict__ out_q)
{
    __shared__ float score_sh[32];
    __shared__ float4 pool4[8][192];          // 24 KB

    const int t = threadIdx.x;
    const int wave = t >> 6;
    const int lane = t & 63;
    const int bid = blockIdx.x;

    const float* rowbase;
    const float* W;
    float bias;
    int len;
    int b, d = 0;
    const bool isq = (bid < Bn);

    if (isq) {
        b = bid;
        len = qlen[b];                                   // 8..32
        W = Wq; bias = bq[0];
        rowbase = hs + ((size_t)b * Ln + 1) * Hn;
    } else {
        const int id = bid - Bn;
        b = id >> 4;
        d = id & 15;
        const int sv = slens[b * Dn + (lane & 15)];      // lanes hold slens[b,:]
        len = __shfl(sv, d, 64);                         // this doc's len
        if (len == 0) {                                  // ~36% of doc blocks
            if (t < 192) {
                float4* o4 = reinterpret_cast<float4*>(out_doc + ((size_t)b * Dn + d) * Hn);
                o4[t] = make_float4(0.f, 0.f, 0.f, 0.f);
            }
            return;
        }
        int pref = 0;
#pragma unroll
        for (int k = 0; k < Dn; ++k)
            pref += (k < d) ? __shfl(sv, k, 64) : 0;
        const int base = qlen[b] + 2 + pref;             // max valid idx 481 < 512
        W = Wd; bias = bd[0];
        rowbase = hs + ((size_t)b * Ln + base) * Hn;
    }

    float4 wv[3];
#pragma unroll
    for (int j = 0; j < 3; ++j)
        wv[j] = *reinterpret_cast<const float4*>(W + (lane + 64 * j) * 4);

    // ---- phase 1: load rows once, score, keep rows in registers ----
    float4 c[4][3];
#pragma unroll
    for (int it = 0; it < 4; ++it) {
        const int s = wave + 8 * it;                     // wave-uniform predicate
        if (s < len) {
            const float* r = rowbase + s * Hn;
#pragma unroll
            for (int j = 0; j < 3; ++j)
                c[it][j] = *reinterpret_cast<const float4*>(r + (lane + 64 * j) * 4);
            float p = c[it][0].x * wv[0].x + c[it][0].y * wv[0].y
                    + c[it][0].z * wv[0].z + c[it][0].w * wv[0].w
                    + c[it][1].x * wv[1].x + c[it][1].y * wv[1].y
                    + c[it][1].z * wv[1].z + c[it][1].w * wv[1].w
                    + c[it][2].x * wv[2].x + c[it][2].y * wv[2].y
                    + c[it][2].z * wv[2].z + c[it][2].w * wv[2].w;
#pragma unroll
            for (int off = 32; off; off >>= 1) p += __shfl_xor(p, off);
            if (lane == 0) score_sh[s] = p;
        }
    }
    __syncthreads();

    // ---- softmax, redundant in every wave (no barrier needed after) ----
    const int si = lane & 31;
    const float raw = (si < len) ? (score_sh[si] + bias) : NEGV;
    float mx = raw;
#pragma unroll
    for (int off = 16; off; off >>= 1) mx = fmaxf(mx, __shfl_xor(mx, off, 32));
    const float e = __expf(raw - mx);
    float den = e;
#pragma unroll
    for (int off = 16; off; off >>= 1) den += __shfl_xor(den, off, 32);
    const float alpha = (si < len) ? (e / den) : 0.f;    // lane i holds alpha[i&31]

    // ---- phase 2: pure register FMA per wave ----
    float4 acc[3];
#pragma unroll
    for (int j = 0; j < 3; ++j) acc[j] = make_float4(0.f, 0.f, 0.f, 0.f);
#pragma unroll
    for (int it = 0; it < 4; ++it) {
        const int s = wave + 8 * it;
        if (s < len) {
            const float a = __shfl(alpha, s, 64);        // s < 32
            acc[0].x += a * c[it][0].x; acc[0].y += a * c[it][0].y;
            acc[0].z += a * c[it][0].z; acc[0].w += a * c[it][0].w;
            acc[1].x += a * c[it][1].x; acc[1].y += a * c[it][1].y;
            acc[1].z += a * c[it][1].z; acc[1].w += a * c[it][1].w;
            acc[2].x += a * c[it][2].x; acc[2].y += a * c[it][2].y;
            acc[2].z += a * c[it][2].z; acc[2].w += a * c[it][2].w;
        }
    }

    // ---- cross-wave combine (single remaining barrier) ----
#pragma unroll
    for (int j = 0; j < 3; ++j) pool4[wave][lane + 64 * j] = acc[j];
    __syncthreads();

    if (t < 192) {
        float4 r = pool4[0][t];
#pragma unroll
        for (int w = 1; w < 8; ++w) {
            const float4 s = pool4[w][t];
            r.x += s.x; r.y += s.y; r.z += s.z; r.w += s.w;
        }
        if (isq) {
            for (int dd = 0; dd < Dn; ++dd) {
                float4* o4 = reinterpret_cast<float4*>(out_q + ((size_t)b * Dn + dd) * Hn);
                o4[t] = r;
            }
        } else {
            float4* o4 = reinterpret_cast<float4*>(out_doc + ((size_t)b * Dn + d) * Hn);
            o4[t] = r;
        }
    }
}

extern "C" void kernel_launch(void* const* d_in, const int* in_sizes, int n_in,
                              void* d_out, int out_size, void* d_ws, size_t ws_size,
                              hipStream_t stream)
{
    const float* hs    = (const float*)d_in[0];   // (B,L,H) f32
    const float* Wd    = (const float*)d_in[1];   // (H,1)
    const float* bd    = (const float*)d_in[2];   // (1,)
    const float* Wq    = (const float*)d_in[3];   // (H,1)
    const float* bq    = (const float*)d_in[4];   // (1,)
    const int*   qlen  = (const int*)d_in[5];     // (B,)
    const int*   slens = (const int*)d_in[6];     // (B,D)

    float* out_doc = (float*)d_out;                       // (B,D,H) doc_pooled
    float* out_q   = out_doc + (size_t)Bn * Dn * Hn;      // (B,D,H) q_bcast

    k_fused<<<Bn + Bn * Dn, 512, 0, stream>>>(hs, Wd, bd, Wq, bq,
                                              qlen, slens, out_doc, out_q);
}